// Round 6
// baseline (608566.699 us; speedup 1.0000x reference)
//
#include <hip/hip_runtime.h>
#include <cstdint>
#include <cstddef>
#include <math.h>

// Exact Viterbi decode: N=512 states, T=8192, M=50257 tokens.
// Forward recurrence computed bit-exactly by a SINGLE WAVE (64 lanes, 8
// columns/lane) — zero __syncthreads, zero cross-wave traffic. Per step, the
// twice-verified exact pruning: L1 = {v_i >= max v - DELTA}; achieved column
// maxima over L1 give T = min_j lb_j; rows with fl(v_i+R) < T (R = global max
// row-max; IEEE add is monotone) cannot win or tie any column; pass2 covers
// {fl(v+R) >= T} \ L1 (rare). Main scan iterates survivors in ASCENDING index
// order (list A = cols 0..255 then list B), so strict-> reproduces first-index
// argmax; pass2 merge uses the full (>, ==&&idx<) compare.
//
// probe_sclk: spins exactly 4e8 shader cycles (wall-capped 0.3 s) so its
// rocprof dur_us reveals the true SCLK: dur=167ms <=> 2.4 GHz.

#define NT 512
#define TT 8192
#define MT 50257
#define DELTA1 0.14f
#define NEG_INF (-3.402823466e38f)

#define BT_L 32                  // backtrace segment length
#define BT_S (TT / BT_L)         // 256 segments

// ---- workspace layout (bytes) ----
#define WS_LOGPI   0u            // 512 f32
#define WS_VLAST   2048u         // 512 f32
#define WS_BOUND   4096u         // 257 i32
#define WS_SINK    5376u         // probe sink
#define WS_ROWMAX  5632u         // 512 f32
#define WS_MAPS    8192u         // 256*512 u16 = 262144
#define WS_LA      270336u       // 512*512 f32 = 1048576 (row-major logA)
#define WS_EMIS    1318912u      // 8192*512 f32 = 16777216
#define WS_BP      18096128u     // 8192*512 u16 = 8388608
#define WS_NEED    26484736u

// Correctly-rounded fp32 logs via fp64 (verified: absmax 0 vs numpy ref).
__global__ void prep_logs(const float* __restrict__ A, const float* __restrict__ Pi,
                          float* __restrict__ lA, float* __restrict__ logPi) {
    int idx = blockIdx.x * blockDim.x + threadIdx.x;
    if (idx < NT * NT) {
        lA[idx] = (float)log((double)A[idx]);
    } else if (idx < NT * NT + NT) {
        int j = idx - NT * NT;
        logPi[j] = (float)log((double)Pi[j]);
    }
}

__global__ void prep_rowmax(const float* __restrict__ lA, float* __restrict__ rowmax) {
    __shared__ float s[4];
    int i = blockIdx.x;
    int t = threadIdx.x;                    // 256 threads
    float m = fmaxf(lA[i * NT + t], lA[i * NT + t + 256]);
    for (int k = 32; k >= 1; k >>= 1) m = fmaxf(m, __shfl_xor(m, k, 64));
    if ((t & 63) == 0) s[t >> 6] = m;
    __syncthreads();
    if (t == 0) {
        float r = fmaxf(fmaxf(s[0], s[1]), fmaxf(s[2], s[3]));
        rowmax[i] = r;
    }
}

__global__ void prep_emis(const float* __restrict__ B, const int* __restrict__ tok,
                          float* __restrict__ emis) {
    int idx = blockIdx.x * blockDim.x + threadIdx.x;   // t*512 + j
    if (idx >= TT * NT) return;
    int t = idx >> 9;
    int j = idx & (NT - 1);
    int tk = tok[t];
    float e;
    if (tk < 0) e = (float)log((double)(1.0f / 512.0f));
    else        e = (float)log((double)B[(size_t)j * MT + tk]);
    emis[idx] = e;
}

// SCLK probe: spin exactly 4e8 shader cycles, wall-capped at 0.3 s (realtime
// clock is a fixed 100 MHz). rocprof dur_us => sclk = 4e8 / dur.
__global__ void probe_sclk(float* __restrict__ sink) {
    long long c0 = clock64();
    long long w0 = wall_clock64();
    long long c = c0;
    for (;;) {
        c = clock64();
        if ((c - c0) >= 400000000LL) break;
        if ((wall_clock64() - w0) >= 30000000LL) break;   // 0.3 s cap
    }
    if (c == 1234567LL) *sink = 1.0f;       // never true; prevents elision
}

// Single-wave exact forward. Lane l owns cols {4l..4l+3} (half A) and
// {256+4l..256+4l+3} (half B). v, e, column-max, argmax all in registers.
__launch_bounds__(64, 1)
__global__ void viterbi_fwd_exact(const float* __restrict__ lA,
                                  const float* __restrict__ rowmax,
                                  const float* __restrict__ emis,
                                  const float* __restrict__ logPi,
                                  unsigned short* __restrict__ bp,
                                  float* __restrict__ vlast) {
    __shared__ float2 SVA[260];              // A-half survivors (v, bitcast idx)
    __shared__ float2 SVB[260];              // B-half survivors
    __shared__ float2 SVX[520];              // pass2 extras
    const int l = threadIdx.x;               // 0..63

    // R = exact global max of rowmax
    float4 r0 = ((const float4*)rowmax)[l];
    float4 r1 = ((const float4*)rowmax)[64 + l];
    float R = fmaxf(fmaxf(fmaxf(r0.x, r0.y), fmaxf(r0.z, r0.w)),
                    fmaxf(fmaxf(r1.x, r1.y), fmaxf(r1.z, r1.w)));
    #pragma unroll
    for (int d = 1; d <= 32; d <<= 1) R = fmaxf(R, __shfl_xor(R, d, 64));

    // v0 = fl(logPi + emis[0])  (single-rounded, == ref)
    float4 p0 = ((const float4*)logPi)[l];
    float4 p1 = ((const float4*)logPi)[64 + l];
    float4 q0 = ((const float4*)emis)[l];
    float4 q1 = ((const float4*)emis)[64 + l];
    float4 vA = make_float4(p0.x + q0.x, p0.y + q0.y, p0.z + q0.z, p0.w + q0.w);
    float4 vB = make_float4(p1.x + q1.x, p1.y + q1.y, p1.z + q1.z, p1.w + q1.w);

    float M = fmaxf(fmaxf(fmaxf(vA.x, vA.y), fmaxf(vA.z, vA.w)),
                    fmaxf(fmaxf(vB.x, vB.y), fmaxf(vB.z, vB.w)));
    #pragma unroll
    for (int d = 1; d <= 32; d <<= 1) M = fmaxf(M, __shfl_xor(M, d, 64));

    const int iA = 4 * l;                    // first A-col of this lane
    const int iB = 256 + 4 * l;              // first B-col

    for (int t = 1; t < TT; ++t) {
        // prefetch e_t (consumed at finalize; latency hidden under the step)
        const float4* ep = (const float4*)(emis + (size_t)t * NT);
        float4 eA = ep[l];
        float4 eB = ep[64 + l];

        // ---- L1 select + in-wave compaction (ascending index by construction)
        float thr = M - DELTA1;
        int a0 = vA.x >= thr, a1 = vA.y >= thr, a2 = vA.z >= thr, a3 = vA.w >= thr;
        int b0p = vB.x >= thr, b1p = vB.y >= thr, b2p = vB.z >= thr, b3p = vB.w >= thr;
        int cA = a0 + a1 + a2 + a3;
        int cB = b0p + b1p + b2p + b3p;
        int xs = cA | (cB << 16);
        #pragma unroll
        for (int d = 1; d <= 32; d <<= 1) {
            int y = __shfl_up(xs, d, 64);
            if (l >= d) xs += y;
        }
        int tot = __shfl(xs, 63, 64);
        int nA = tot & 0xffff, nB = tot >> 16;
        int wA = (xs & 0xffff) - cA;
        int wB = (xs >> 16) - cB;
        if (a0)  SVA[wA++] = make_float2(vA.x, __int_as_float(iA + 0));
        if (a1)  SVA[wA++] = make_float2(vA.y, __int_as_float(iA + 1));
        if (a2)  SVA[wA++] = make_float2(vA.z, __int_as_float(iA + 2));
        if (a3)  SVA[wA]   = make_float2(vA.w, __int_as_float(iA + 3));
        if (b0p) SVB[wB++] = make_float2(vB.x, __int_as_float(iB + 0));
        if (b1p) SVB[wB++] = make_float2(vB.y, __int_as_float(iB + 1));
        if (b2p) SVB[wB++] = make_float2(vB.z, __int_as_float(iB + 2));
        if (b3p) SVB[wB]   = make_float2(vB.w, __int_as_float(iB + 3));

        // ---- main scan (ascending index => strict-> is exact first-index)
        float m0 = NEG_INF, m1 = NEG_INF, m2 = NEG_INF, m3 = NEG_INF;
        float m4 = NEG_INF, m5 = NEG_INF, m6 = NEG_INF, m7 = NEG_INF;
        int   c0i = 0, c1i = 0, c2i = 0, c3i = 0, c4i = 0, c5i = 0, c6i = 0, c7i = 0;
        #pragma unroll 2
        for (int s = 0; s < nA; ++s) {
            float2 q = SVA[s];               // same addr all lanes -> broadcast
            float vs = q.x;
            int   is = __builtin_amdgcn_readfirstlane(__float_as_int(q.y));
            const float4* row = (const float4*)(lA + ((size_t)is << 9));
            float4 x0 = row[l];              // cols 4l..4l+3   (coalesced 1KB)
            float4 x1 = row[64 + l];         // cols 256+4l..   (coalesced 1KB)
            float sc;
            sc = vs + x0.x; if (sc > m0) { m0 = sc; c0i = is; }
            sc = vs + x0.y; if (sc > m1) { m1 = sc; c1i = is; }
            sc = vs + x0.z; if (sc > m2) { m2 = sc; c2i = is; }
            sc = vs + x0.w; if (sc > m3) { m3 = sc; c3i = is; }
            sc = vs + x1.x; if (sc > m4) { m4 = sc; c4i = is; }
            sc = vs + x1.y; if (sc > m5) { m5 = sc; c5i = is; }
            sc = vs + x1.z; if (sc > m6) { m6 = sc; c6i = is; }
            sc = vs + x1.w; if (sc > m7) { m7 = sc; c7i = is; }
        }
        #pragma unroll 2
        for (int s = 0; s < nB; ++s) {
            float2 q = SVB[s];
            float vs = q.x;
            int   is = __builtin_amdgcn_readfirstlane(__float_as_int(q.y));
            const float4* row = (const float4*)(lA + ((size_t)is << 9));
            float4 x0 = row[l];
            float4 x1 = row[64 + l];
            float sc;
            sc = vs + x0.x; if (sc > m0) { m0 = sc; c0i = is; }
            sc = vs + x0.y; if (sc > m1) { m1 = sc; c1i = is; }
            sc = vs + x0.z; if (sc > m2) { m2 = sc; c2i = is; }
            sc = vs + x0.w; if (sc > m3) { m3 = sc; c3i = is; }
            sc = vs + x1.x; if (sc > m4) { m4 = sc; c4i = is; }
            sc = vs + x1.y; if (sc > m5) { m5 = sc; c5i = is; }
            sc = vs + x1.z; if (sc > m6) { m6 = sc; c6i = is; }
            sc = vs + x1.w; if (sc > m7) { m7 = sc; c7i = is; }
        }

        // ---- T = min over all columns of achieved maxima
        float T = fminf(fminf(fminf(m0, m1), fminf(m2, m3)),
                        fminf(fminf(m4, m5), fminf(m6, m7)));
        #pragma unroll
        for (int d = 1; d <= 32; d <<= 1) T = fminf(T, __shfl_xor(T, d, 64));

        // ---- pass2 extras: {fl(v+R) >= T} \ L1  (usually empty)
        float g0 = vA.x + R, g1 = vA.y + R, g2 = vA.z + R, g3 = vA.w + R;
        float g4 = vB.x + R, g5 = vB.y + R, g6 = vB.z + R, g7 = vB.w + R;
        int px0 = (g0 >= T) & !a0,  px1 = (g1 >= T) & !a1;
        int px2 = (g2 >= T) & !a2,  px3 = (g3 >= T) & !a3;
        int px4 = (g4 >= T) & !b0p, px5 = (g5 >= T) & !b1p;
        int px6 = (g6 >= T) & !b2p, px7 = (g7 >= T) & !b3p;
        unsigned long long anyx =
            __ballot((px0 | px1 | px2 | px3 | px4 | px5 | px6 | px7) != 0);
        if (anyx != 0ull) {
            int cXA = px0 + px1 + px2 + px3;
            int cXB = px4 + px5 + px6 + px7;
            int zs = cXA | (cXB << 16);
            #pragma unroll
            for (int d = 1; d <= 32; d <<= 1) {
                int y = __shfl_up(zs, d, 64);
                if (l >= d) zs += y;
            }
            int tot2 = __shfl(zs, 63, 64);
            int nXA = tot2 & 0xffff;
            int nX  = nXA + (tot2 >> 16);
            int uA = (zs & 0xffff) - cXA;
            int uB = nXA + (zs >> 16) - cXB;
            if (px0) SVX[uA++] = make_float2(vA.x, __int_as_float(iA + 0));
            if (px1) SVX[uA++] = make_float2(vA.y, __int_as_float(iA + 1));
            if (px2) SVX[uA++] = make_float2(vA.z, __int_as_float(iA + 2));
            if (px3) SVX[uA]   = make_float2(vA.w, __int_as_float(iA + 3));
            if (px4) SVX[uB++] = make_float2(vB.x, __int_as_float(iB + 0));
            if (px5) SVX[uB++] = make_float2(vB.y, __int_as_float(iB + 1));
            if (px6) SVX[uB++] = make_float2(vB.z, __int_as_float(iB + 2));
            if (px7) SVX[uB]   = make_float2(vB.w, __int_as_float(iB + 3));
            for (int s = 0; s < nX; ++s) {   // full compare (index-tie exact)
                float2 q = SVX[s];
                float vs = q.x;
                int   is = __builtin_amdgcn_readfirstlane(__float_as_int(q.y));
                const float4* row = (const float4*)(lA + ((size_t)is << 9));
                float4 x0 = row[l];
                float4 x1 = row[64 + l];
                float sc;
                sc = vs + x0.x; if (sc > m0 || (sc == m0 && is < c0i)) { m0 = sc; c0i = is; }
                sc = vs + x0.y; if (sc > m1 || (sc == m1 && is < c1i)) { m1 = sc; c1i = is; }
                sc = vs + x0.z; if (sc > m2 || (sc == m2 && is < c2i)) { m2 = sc; c2i = is; }
                sc = vs + x0.w; if (sc > m3 || (sc == m3 && is < c3i)) { m3 = sc; c3i = is; }
                sc = vs + x1.x; if (sc > m4 || (sc == m4 && is < c4i)) { m4 = sc; c4i = is; }
                sc = vs + x1.y; if (sc > m5 || (sc == m5 && is < c5i)) { m5 = sc; c5i = is; }
                sc = vs + x1.z; if (sc > m6 || (sc == m6 && is < c6i)) { m6 = sc; c6i = is; }
                sc = vs + x1.w; if (sc > m7 || (sc == m7 && is < c7i)) { m7 = sc; c7i = is; }
            }
        }

        // ---- finalize: vn = fl(colmax + e), store bp, next-step M
        vA = make_float4(m0 + eA.x, m1 + eA.y, m2 + eA.z, m3 + eA.w);
        vB = make_float4(m4 + eB.x, m5 + eB.y, m6 + eB.z, m7 + eB.w);
        unsigned short* bpt = bp + (size_t)t * NT;
        uint2 wv0, wv1;
        wv0.x = (unsigned)(c0i | (c1i << 16));
        wv0.y = (unsigned)(c2i | (c3i << 16));
        wv1.x = (unsigned)(c4i | (c5i << 16));
        wv1.y = (unsigned)(c6i | (c7i << 16));
        ((uint2*)bpt)[l]        = wv0;       // cols 4l..4l+3
        ((uint2*)(bpt + 256))[l] = wv1;      // cols 256+4l..256+4l+3
        if (t == TT - 1) {
            ((float4*)vlast)[l]      = vA;
            ((float4*)vlast)[64 + l] = vB;
        }
        M = fmaxf(fmaxf(fmaxf(vA.x, vA.y), fmaxf(vA.z, vA.w)),
                  fmaxf(fmaxf(vB.x, vB.y), fmaxf(vB.z, vB.w)));
        #pragma unroll
        for (int d = 1; d <= 32; d <<= 1) M = fmaxf(M, __shfl_xor(M, d, 64));
    }
}

// ---- backtrace: per-segment map composition (verified exact) ----
__launch_bounds__(NT, 1)
__global__ void bt_maps(const unsigned short* __restrict__ bp,
                        unsigned short* __restrict__ maps) {
    __shared__ unsigned short bps[BT_L * NT];
    const int s = blockIdx.x;
    const int tlo = BT_L * s + 1;
    int thi = BT_L * (s + 1); if (thi > TT - 1) thi = TT - 1;
    const int nt = thi - tlo + 1;
    for (int k = threadIdx.x; k < nt * NT; k += NT)
        bps[k] = bp[(size_t)tlo * NT + k];
    __syncthreads();
    int cur = threadIdx.x;
    for (int r = nt - 1; r >= 0; --r) cur = bps[r * NT + cur];
    maps[s * NT + threadIdx.x] = (unsigned short)cur;
}

__launch_bounds__(NT, 1)
__global__ void bt_bound(const float* __restrict__ vlast,
                         const unsigned short* __restrict__ maps,
                         int* __restrict__ bound) {
    __shared__ float sv[NT];
    __shared__ int   si[NT];
    int j = threadIdx.x;
    sv[j] = vlast[j]; si[j] = j;
    __syncthreads();
    for (int off = NT / 2; off > 0; off >>= 1) {
        if (j < off) {
            float v2 = sv[j + off]; int i2 = si[j + off];
            if (v2 > sv[j] || (v2 == sv[j] && i2 < si[j])) { sv[j] = v2; si[j] = i2; }
        }
        __syncthreads();
    }
    if (j == 0) {
        int cur = si[0];
        bound[BT_S] = cur;
        for (int s = BT_S - 1; s >= 0; --s) {
            cur = maps[s * NT + cur];
            bound[s] = cur;
        }
    }
}

__launch_bounds__(NT, 1)
__global__ void bt_path(const unsigned short* __restrict__ bp,
                        const int* __restrict__ bound,
                        int* __restrict__ path) {
    __shared__ unsigned short bps[BT_L * NT];
    const int s = blockIdx.x;
    const int tlo = BT_L * s + 1;
    int thi = BT_L * (s + 1); if (thi > TT - 1) thi = TT - 1;
    const int nt = thi - tlo + 1;
    for (int k = threadIdx.x; k < nt * NT; k += NT)
        bps[k] = bp[(size_t)tlo * NT + k];
    __syncthreads();
    if (threadIdx.x == 0) {
        int cur = bound[s + 1];
        if (s == BT_S - 1) path[TT - 1] = cur;
        for (int r = nt - 1; r >= 0; --r) {
            cur = bps[r * NT + cur];
            path[tlo - 1 + r] = cur;
        }
    }
}

extern "C" void kernel_launch(void* const* d_in, const int* in_sizes, int n_in,
                              void* d_out, int out_size, void* d_ws, size_t ws_size,
                              hipStream_t stream) {
    const int*   tok = (const int*)d_in[0];
    const float* A   = (const float*)d_in[1];
    const float* B   = (const float*)d_in[2];
    const float* Pi  = (const float*)d_in[3];
    int* path = (int*)d_out;
    char* ws = (char*)d_ws;
    if (ws_size < (size_t)WS_NEED) return;

    float* logPi          = (float*)(ws + WS_LOGPI);
    float* vlast          = (float*)(ws + WS_VLAST);
    int*   bound          = (int*)(ws + WS_BOUND);
    float* sink           = (float*)(ws + WS_SINK);
    float* rowmax         = (float*)(ws + WS_ROWMAX);
    unsigned short* maps  = (unsigned short*)(ws + WS_MAPS);
    float* lA             = (float*)(ws + WS_LA);
    float* emis           = (float*)(ws + WS_EMIS);
    unsigned short* bpp   = (unsigned short*)(ws + WS_BP);

    prep_logs  <<<(NT * NT + NT + 255) / 256, 256, 0, stream>>>(A, Pi, lA, logPi);
    prep_emis  <<<(TT * NT) / 256,            256, 0, stream>>>(B, tok, emis);
    prep_rowmax<<<NT, 256, 0, stream>>>(lA, rowmax);
    viterbi_fwd_exact<<<1, 64, 0, stream>>>(lA, rowmax, emis, logPi, bpp, vlast);
    bt_maps  <<<BT_S, NT, 0, stream>>>(bpp, maps);
    bt_bound <<<1,    NT, 0, stream>>>(vlast, maps, bound);
    bt_path  <<<BT_S, NT, 0, stream>>>(bpp, bound, path);
    probe_sclk<<<1, 64, 0, stream>>>(sink);
}

// Round 7
// 91964.520 us; speedup vs baseline: 6.6174x; 6.6174x over previous
//
#include <hip/hip_runtime.h>
#include <cstdint>
#include <cstddef>
#include <math.h>

// Exact Viterbi decode: N=512 states, T=8192, M=50257 tokens.
// Forward recurrence computed bit-exactly by ONE 512-thread workgroup
// (8 waves; thread j owns column j; v_j lives in a REGISTER only).
// Exactness-preserving pruning (same proof as R4/R6, twice HW-verified):
//   SV  = union over waves of {i : v_i >= wavemax - DELTA_W}   (heuristic set)
//   T   = min_j (achieved column max over SV)                  (achieved bound)
//   rows with fl(v_i + R) < T (R = global max row-max; IEEE add monotone)
//   cannot win or tie any column; extras {fl(v+R) >= T} \ SV handled exactly
//   on a rare path (margin analysis: requires v >= vmax-0.107 => always
//   selected per-wave since DELTA_W = 0.15 > 0.107).
// All merges use (value strict >, then smaller index) => exact first-index
// argmax under nondeterministic survivor-segment order.

#define NT 512
#define TT 8192
#define MT 50257
#define DELTA_W 0.15f
#define NEG_INF (-3.402823466e38f)

#define BT_L 32                  // backtrace segment length
#define BT_S (TT / BT_L)         // 256 segments

// ---- workspace layout (bytes) ----
#define WS_LOGPI   0u            // 512 f32
#define WS_VLAST   2048u         // 512 f32
#define WS_BOUND   4096u         // 257 i32
#define WS_ROWMAX  5632u         // 512 f32
#define WS_MAPS    8192u         // 256*512 u16 = 262144
#define WS_LA      270336u       // 512*512 f32 = 1048576 (row-major logA)
#define WS_EMIS    1318912u      // 8192*512 f32 = 16777216
#define WS_BP      18096128u     // 8192*512 u16 = 8388608
#define WS_NEED    26484736u

// Correctly-rounded fp32 logs via fp64 (verified: absmax 0 vs numpy ref).
__global__ void prep_logs(const float* __restrict__ A, const float* __restrict__ Pi,
                          float* __restrict__ lA, float* __restrict__ logPi) {
    int idx = blockIdx.x * blockDim.x + threadIdx.x;
    if (idx < NT * NT) {
        lA[idx] = (float)log((double)A[idx]);
    } else if (idx < NT * NT + NT) {
        int j = idx - NT * NT;
        logPi[j] = (float)log((double)Pi[j]);
    }
}

__global__ void prep_rowmax(const float* __restrict__ lA, float* __restrict__ rowmax) {
    __shared__ float s[4];
    int i = blockIdx.x;
    int t = threadIdx.x;                    // 256 threads
    float m = fmaxf(lA[i * NT + t], lA[i * NT + t + 256]);
    for (int k = 32; k >= 1; k >>= 1) m = fmaxf(m, __shfl_xor(m, k, 64));
    if ((t & 63) == 0) s[t >> 6] = m;
    __syncthreads();
    if (t == 0) {
        float r = fmaxf(fmaxf(s[0], s[1]), fmaxf(s[2], s[3]));
        rowmax[i] = r;
    }
}

__global__ void prep_emis(const float* __restrict__ B, const int* __restrict__ tok,
                          float* __restrict__ emis) {
    int idx = blockIdx.x * blockDim.x + threadIdx.x;   // t*512 + j
    if (idx >= TT * NT) return;
    int t = idx >> 9;
    int j = idx & (NT - 1);
    int tk = tok[t];
    float e;
    if (tk < 0) e = (float)log((double)(1.0f / 512.0f));
    else        e = (float)log((double)B[(size_t)j * MT + tk]);
    emis[idx] = e;
}

// 512 threads / 8 waves. 3 barriers per step (common path).
__launch_bounds__(NT, 1)
__global__ void viterbi_fwd_exact(const float* __restrict__ lA,
                                  const float* __restrict__ rowmax,
                                  const float* __restrict__ emis,
                                  const float* __restrict__ logPi,
                                  unsigned short* __restrict__ bp,
                                  float* __restrict__ vlast) {
    __shared__ float2 SV[2][560];            // double-buffered survivors (v, idx bits)
    __shared__ float2 SVX[560];              // extras (rare)
    __shared__ alignas(16) float redR[8];    // rowmax partials
    __shared__ alignas(16) float redT[8];    // T partials
    __shared__ int nCtr[2];
    __shared__ int nCtrX;

    const int tid  = threadIdx.x;
    const int j    = tid;                    // column AND row owned
    const int lane = tid & 63;
    const int wave = tid >> 6;               // 0..7
    const unsigned long long below = (1ull << lane) - 1ull;
    const float* __restrict__ lAj = lA + j;

    // ---- preamble: warm lA into local L1/L2; R; counters; v0 ----
    float acc = 0.0f;
    {
        const float4* lAf4 = (const float4*)lA;
        for (int k = tid; k < (NT * NT) / 4; k += NT) acc += lAf4[k].x;
    }
    float r = rowmax[j];
    #pragma unroll
    for (int d = 1; d <= 32; d <<= 1) r = fmaxf(r, __shfl_xor(r, d, 64));
    if (lane == 0) redR[wave] = r;
    if (tid == 0) { nCtr[0] = 0; nCtr[1] = 0; nCtrX = 0; }
    __syncthreads();
    float4 rr0 = *(const float4*)redR;
    float4 rr1 = *(const float4*)(redR + 4);
    const float R = fmaxf(fmaxf(fmaxf(rr0.x, rr0.y), fmaxf(rr0.z, rr0.w)),
                          fmaxf(fmaxf(rr1.x, rr1.y), fmaxf(rr1.z, rr1.w)));
    if (acc == 1.2345e30f && j == 511) SVX[0].x = acc;   // keep warm loads alive

    float v = logPi[j] + emis[j];            // exact v0 (single-rounded == ref)

    for (int t = 1; t < TT; ++t) {
        const int p = t & 1;
        // ---- PH1: emis issue; per-wave select; compact ----
        float e = emis[(size_t)t * NT + j];  // consumed at finalize
        float wm = v;
        #pragma unroll
        for (int d = 1; d <= 32; d <<= 1) wm = fmaxf(wm, __shfl_xor(wm, d, 64));
        bool pred = (v >= wm - DELTA_W);
        unsigned long long mk = __ballot(pred);
        int base = 0;
        if (lane == 0) base = atomicAdd(&nCtr[p], __popcll(mk));
        base = __shfl(base, 0, 64);
        if (pred) SV[p][base + __popcll(mk & below)] = make_float2(v, __int_as_float(j));
        __syncthreads();                     // B1

        // ---- PH2a: scan survivors (chunks of 16); T partials; resets ----
        const int n = nCtr[p];               // >= 8 (each wave's max row selected)
        float mval = NEG_INF;
        int   bidx = 0x7fffffff;
        for (int s0 = 0; s0 < n; s0 += 16) {
            float2 q[16];
            #pragma unroll
            for (int k = 0; k < 16; ++k) {
                int s = s0 + k;
                q[k] = SV[p][s < n ? s : n - 1];    // clamp: dup merge is idempotent
            }
            float a[16];
            #pragma unroll
            for (int k = 0; k < 16; ++k)
                a[k] = lAj[(size_t)__float_as_int(q[k].y) * NT];
            #pragma unroll
            for (int k = 0; k < 16; ++k) {
                float sc = q[k].x + a[k];           // single-rounded add == ref
                int   is = __float_as_int(q[k].y);
                if (sc > mval || (sc == mval && is < bidx)) { mval = sc; bidx = is; }
            }
        }
        float tmin = mval;
        #pragma unroll
        for (int d = 1; d <= 32; d <<= 1) tmin = fminf(tmin, __shfl_xor(tmin, d, 64));
        if (lane == 0) redT[wave] = tmin;
        if (tid == 0) { nCtr[p ^ 1] = 0; nCtrX = 0; }   // safe: old reads pre-B1
        __syncthreads();                     // B2

        // ---- PH2b: T; extras compact (rare) ----
        float4 t0 = *(const float4*)redT;
        float4 t1 = *(const float4*)(redT + 4);
        float T = fminf(fminf(fminf(t0.x, t0.y), fminf(t0.z, t0.w)),
                        fminf(fminf(t1.x, t1.y), fminf(t1.z, t1.w)));
        bool px = (v + R >= T) && !pred;     // fl(v+R) monotone upper bound
        unsigned long long mkx = __ballot(px);
        if (mkx != 0ull) {                   // ~never
            int bx = 0;
            if (lane == 0) bx = atomicAdd(&nCtrX, __popcll(mkx));
            bx = __shfl(bx, 0, 64);
            if (px) SVX[bx + __popcll(mkx & below)] = make_float2(v, __int_as_float(j));
        }
        __syncthreads();                     // B3

        // ---- PH2c: rare extras scan; finalize ----
        const int nX = nCtrX;                // block-uniform
        if (nX > 0) {
            for (int s0 = 0; s0 < nX; s0 += 16) {
                float2 q[16];
                #pragma unroll
                for (int k = 0; k < 16; ++k) {
                    int s = s0 + k;
                    q[k] = SVX[s < nX ? s : nX - 1];
                }
                float a[16];
                #pragma unroll
                for (int k = 0; k < 16; ++k)
                    a[k] = lAj[(size_t)__float_as_int(q[k].y) * NT];
                #pragma unroll
                for (int k = 0; k < 16; ++k) {
                    float sc = q[k].x + a[k];
                    int   is = __float_as_int(q[k].y);
                    if (sc > mval || (sc == mval && is < bidx)) { mval = sc; bidx = is; }
                }
            }
        }
        float vn = mval + e;                 // single-rounded == ref
        bp[(size_t)t * NT + j] = (unsigned short)bidx;
        if (t == TT - 1) vlast[j] = vn;
        v = vn;
    }
}

// ---- backtrace: per-segment map composition (verified exact) ----
__launch_bounds__(NT, 1)
__global__ void bt_maps(const unsigned short* __restrict__ bp,
                        unsigned short* __restrict__ maps) {
    __shared__ unsigned short bps[BT_L * NT];
    const int s = blockIdx.x;
    const int tlo = BT_L * s + 1;
    int thi = BT_L * (s + 1); if (thi > TT - 1) thi = TT - 1;
    const int nt = thi - tlo + 1;
    for (int k = threadIdx.x; k < nt * NT; k += NT)
        bps[k] = bp[(size_t)tlo * NT + k];
    __syncthreads();
    int cur = threadIdx.x;
    for (int r = nt - 1; r >= 0; --r) cur = bps[r * NT + cur];
    maps[s * NT + threadIdx.x] = (unsigned short)cur;
}

__launch_bounds__(NT, 1)
__global__ void bt_bound(const float* __restrict__ vlast,
                         const unsigned short* __restrict__ maps,
                         int* __restrict__ bound) {
    __shared__ float sv[NT];
    __shared__ int   si[NT];
    int j = threadIdx.x;
    sv[j] = vlast[j]; si[j] = j;
    __syncthreads();
    for (int off = NT / 2; off > 0; off >>= 1) {
        if (j < off) {
            float v2 = sv[j + off]; int i2 = si[j + off];
            if (v2 > sv[j] || (v2 == sv[j] && i2 < si[j])) { sv[j] = v2; si[j] = i2; }
        }
        __syncthreads();
    }
    if (j == 0) {
        int cur = si[0];
        bound[BT_S] = cur;
        for (int s = BT_S - 1; s >= 0; --s) {
            cur = maps[s * NT + cur];
            bound[s] = cur;
        }
    }
}

__launch_bounds__(NT, 1)
__global__ void bt_path(const unsigned short* __restrict__ bp,
                        const int* __restrict__ bound,
                        int* __restrict__ path) {
    __shared__ unsigned short bps[BT_L * NT];
    const int s = blockIdx.x;
    const int tlo = BT_L * s + 1;
    int thi = BT_L * (s + 1); if (thi > TT - 1) thi = TT - 1;
    const int nt = thi - tlo + 1;
    for (int k = threadIdx.x; k < nt * NT; k += NT)
        bps[k] = bp[(size_t)tlo * NT + k];
    __syncthreads();
    if (threadIdx.x == 0) {
        int cur = bound[s + 1];
        if (s == BT_S - 1) path[TT - 1] = cur;
        for (int r = nt - 1; r >= 0; --r) {
            cur = bps[r * NT + cur];
            path[tlo - 1 + r] = cur;
        }
    }
}

extern "C" void kernel_launch(void* const* d_in, const int* in_sizes, int n_in,
                              void* d_out, int out_size, void* d_ws, size_t ws_size,
                              hipStream_t stream) {
    const int*   tok = (const int*)d_in[0];
    const float* A   = (const float*)d_in[1];
    const float* B   = (const float*)d_in[2];
    const float* Pi  = (const float*)d_in[3];
    int* path = (int*)d_out;
    char* ws = (char*)d_ws;
    if (ws_size < (size_t)WS_NEED) return;

    float* logPi          = (float*)(ws + WS_LOGPI);
    float* vlast          = (float*)(ws + WS_VLAST);
    int*   bound          = (int*)(ws + WS_BOUND);
    float* rowmax         = (float*)(ws + WS_ROWMAX);
    unsigned short* maps  = (unsigned short*)(ws + WS_MAPS);
    float* lA             = (float*)(ws + WS_LA);
    float* emis           = (float*)(ws + WS_EMIS);
    unsigned short* bpp   = (unsigned short*)(ws + WS_BP);

    prep_logs  <<<(NT * NT + NT + 255) / 256, 256, 0, stream>>>(A, Pi, lA, logPi);
    prep_emis  <<<(TT * NT) / 256,            256, 0, stream>>>(B, tok, emis);
    prep_rowmax<<<NT, 256, 0, stream>>>(lA, rowmax);
    viterbi_fwd_exact<<<1, NT, 0, stream>>>(lA, rowmax, emis, logPi, bpp, vlast);
    bt_maps  <<<BT_S, NT, 0, stream>>>(bpp, maps);
    bt_bound <<<1,    NT, 0, stream>>>(vlast, maps, bound);
    bt_path  <<<BT_S, NT, 0, stream>>>(bpp, bound, path);
}